// Round 4
// baseline (149.244 us; speedup 1.0000x reference)
//
#include <hip/hip_runtime.h>
#include <hip/hip_bf16.h>

#define BATCH 16384
#define WPAD 72   // halves per LDS row: 144B rows, 16B-aligned

typedef __attribute__((ext_vector_type(8))) short short8;
typedef __attribute__((ext_vector_type(4))) short short4v;
typedef __attribute__((ext_vector_type(4))) unsigned short ushort4v;
typedef __attribute__((ext_vector_type(4))) float float4v;

__device__ __forceinline__ unsigned int packbf2(float a, float b) {
    union { __hip_bfloat162 h; unsigned int u; } v;
    v.h = __float22bfloat162_rn(make_float2(a, b));
    return v.u;
}
__device__ __forceinline__ unsigned short f2bf(float a) {
    union { __hip_bfloat16 h; unsigned short u; } v;
    v.h = __float2bfloat16(a);
    return v.u;
}

// Transposed-chain fused MLP (fp32 in, bf16 MFMA compute, fp32 out):
//   H1T = relu(W1T @ XT + b1)   mfma_f32_16x16x32_bf16 (A=W1T LDS, B=XT from global, cvt to bf16)
//   H2T = relu(W2T @ H1T + b2)  mfma_f32_16x16x16bf16_1k (B = layer-1 C/D regs, packed)
//   OutT = W3T @ H2T + b3       mfma_f32_16x16x16bf16_1k (A rows >= 2 zero)
// C/D layout (col=lane&15,row=quad*4+reg) == B layout of the K-gran-4 _1k shape -> pure register chain.
// Cross-validated: this path and the all-verified-layout LDS path produce identical outputs (R2==R3).
__global__ __launch_bounds__(256) void arnet_kernel(
    const float* __restrict__ x,    // [16384,64]
    const float* __restrict__ w0,   // [1,64]
    const float* __restrict__ b0,   // [64]
    const float* __restrict__ v0,   // [64,2]
    const float* __restrict__ c0,   // [2]
    const float* __restrict__ W1,   // [63,64,64]  [d][h]
    const float* __restrict__ B1,   // [63,64]
    const float* __restrict__ W2,   // [63,64,64]  [h][g]
    const float* __restrict__ B2,   // [63,64]
    const float* __restrict__ W3,   // [63,64,2]   [g][o]
    const float* __restrict__ B3,   // [63,2]
    float* __restrict__ out)        // fp32 [2][16384][64]
{
    const int bi   = blockIdx.x;
    const int net  = bi >> 5;   // output column 0..63
    const int tile = bi & 31;   // 512-row tile (XCD = tile & 7 for every net -> shared L2)
    const int t    = threadIdx.x;

    if (net == 0) {
        float s = 0.f, tr = 0.f;
        #pragma unroll 8
        for (int j = 0; j < 64; ++j) {
            float h = fmaxf(w0[j] + b0[j], 0.f);
            s  += h * v0[2 * j];
            tr += h * v0[2 * j + 1];
        }
        s += c0[0];
        tr += c0[1];
        s = fminf(fmaxf(s, -5.f), 5.f);
        const size_t r0 = (size_t)tile * 512;
        out[(r0 + t) * 64] = s;
        out[(size_t)BATCH * 64 + (r0 + t) * 64] = tr;
        out[(r0 + 256 + t) * 64] = s;
        out[(size_t)BATCH * 64 + (r0 + 256 + t) * 64] = tr;
        return;
    }

    __shared__ unsigned short sW1T[64 * WPAD];  // [h][d]  d contiguous (K of L1)
    __shared__ unsigned short sW2T[64 * WPAD];  // [g][h]  h contiguous (K of L2)
    __shared__ unsigned short sW3T[2 * 64];     // [o][g]  g contiguous (K of L3)
    __shared__ float sB1[64];
    __shared__ float sB2[64];

    const int kn = net - 1;

    // ---- stage transposed weights (fp32 -> bf16), mask W1 cols d >= net ----
    {
        const int hb = (t & 15) * 4;
        const int jb = (t >> 4) * 4;
        const float* src1 = W1 + kn * 4096;
        const float* src2 = W2 + kn * 4096;
        float4v a[4], b[4];
        #pragma unroll
        for (int jj = 0; jj < 4; ++jj) {
            a[jj] = *(const float4v*)(src1 + (jb + jj) * 64 + hb);
            if (jb + jj >= net) a[jj] = (float4v)0.f;   // autoregressive mask: valid d < net
            b[jj] = *(const float4v*)(src2 + (jb + jj) * 64 + hb);
        }
        #pragma unroll
        for (int hh = 0; hh < 4; ++hh) {
            ushort4v ra, rb;
            #pragma unroll
            for (int jj = 0; jj < 4; ++jj) { ra[jj] = f2bf(a[jj][hh]); rb[jj] = f2bf(b[jj][hh]); }
            *(ushort4v*)(&sW1T[(hb + hh) * WPAD + jb]) = ra;   // sW1T[h][d]
            *(ushort4v*)(&sW2T[(hb + hh) * WPAD + jb]) = rb;   // sW2T[g][h]
        }
    }
    if (t < 64) {
        sW3T[t]      = f2bf(W3[kn * 128 + t * 2]);      // [o=0][g]
        sW3T[64 + t] = f2bf(W3[kn * 128 + t * 2 + 1]);  // [o=1][g]
        sB1[t] = B1[kn * 64 + t];
        sB2[t] = B2[kn * 64 + t];
    }
    const float b30 = B3[kn * 2];
    const float b31 = B3[kn * 2 + 1];
    __syncthreads();

    const int lane = t & 63;
    const int w    = t >> 6;
    const int lq   = lane & 15;
    const int quad = lane >> 4;

    for (int pass = 0; pass < 2; ++pass) {
        const int rowbase = tile * 512 + pass * 256 + w * 64;

        // B of L1 = XT: lane holds batch-col n=lq, 8 contiguous features -> global fp32, pack bf16
        short8 xf[4][2];
        #pragma unroll
        for (int tm = 0; tm < 4; ++tm) {
            const float* xr = x + (size_t)(rowbase + 16 * tm + lq) * 64 + quad * 8;
            #pragma unroll
            for (int half = 0; half < 2; ++half) {
                float4v f0 = *(const float4v*)(xr + 32 * half);
                float4v f1 = *(const float4v*)(xr + 32 * half + 4);
                union { short8 s; unsigned int u[4]; } p;
                p.u[0] = packbf2(f0[0], f0[1]);
                p.u[1] = packbf2(f0[2], f0[3]);
                p.u[2] = packbf2(f1[0], f1[1]);
                p.u[3] = packbf2(f1[2], f1[3]);
                xf[tm][half] = p.s;
            }
        }

        // layer-2 accumulators, bias-initialized (g = quad*4+reg+16*tg)
        float4v acc2[4][4];
        #pragma unroll
        for (int tg = 0; tg < 4; ++tg) {
            float4v bias2 = *(const float4v*)(&sB2[quad * 4 + 16 * tg]);
            #pragma unroll
            for (int tm = 0; tm < 4; ++tm) acc2[tg][tm] = bias2;
        }

        #pragma unroll
        for (int th = 0; th < 4; ++th) {
            // ---- layer 1, h-block th ----
            float4v bias1 = *(const float4v*)(&sB1[quad * 4 + 16 * th]);
            short8 a10 = *(const short8*)(&sW1T[(lq + 16 * th) * WPAD + quad * 8]);
            short8 a11 = *(const short8*)(&sW1T[(lq + 16 * th) * WPAD + quad * 8 + 32]);
            float4v acc1[4];
            #pragma unroll
            for (int tm = 0; tm < 4; ++tm) {
                acc1[tm] = bias1;
                acc1[tm] = __builtin_amdgcn_mfma_f32_16x16x32_bf16(a10, xf[tm][0], acc1[tm], 0, 0, 0);
                acc1[tm] = __builtin_amdgcn_mfma_f32_16x16x32_bf16(a11, xf[tm][1], acc1[tm], 0, 0, 0);
            }
            // relu + pack: C/D rows (h=16th+quad*4+r) become _1k B-frag k=quad*4+r, K-block th
            short4v bf1[4];
            #pragma unroll
            for (int tm = 0; tm < 4; ++tm) {
                union { short4v s; unsigned int u[2]; } pk;
                pk.u[0] = packbf2(fmaxf(acc1[tm][0], 0.f), fmaxf(acc1[tm][1], 0.f));
                pk.u[1] = packbf2(fmaxf(acc1[tm][2], 0.f), fmaxf(acc1[tm][3], 0.f));
                bf1[tm] = pk.s;
            }
            // ---- layer 2 partial: accumulate K-block th ----
            #pragma unroll
            for (int tg = 0; tg < 4; ++tg) {
                short4v a2 = *(const short4v*)(&sW2T[(lq + 16 * tg) * WPAD + quad * 4 + 16 * th]);
                #pragma unroll
                for (int tm = 0; tm < 4; ++tm)
                    acc2[tg][tm] = __builtin_amdgcn_mfma_f32_16x16x16bf16_1k(a2, bf1[tm], acc2[tg][tm], 0, 0, 0);
            }
        }

        // ---- layer 3 ----
        float4v acc3[4];
        #pragma unroll
        for (int tm = 0; tm < 4; ++tm) {
            acc3[tm][0] = b30; acc3[tm][1] = b31; acc3[tm][2] = 0.f; acc3[tm][3] = 0.f;
        }
        #pragma unroll
        for (int tg = 0; tg < 4; ++tg) {
            short4v a3 = (short4v)0;                       // A rows >= 2 contribute zero
            if (lq < 2) a3 = *(const short4v*)(&sW3T[lq * 64 + quad * 4 + 16 * tg]);
            #pragma unroll
            for (int tm = 0; tm < 4; ++tm) {
                union { short4v s; unsigned int u[2]; } pk;
                pk.u[0] = packbf2(fmaxf(acc2[tg][tm][0], 0.f), fmaxf(acc2[tg][tm][1], 0.f));
                pk.u[1] = packbf2(fmaxf(acc2[tg][tm][2], 0.f), fmaxf(acc2[tg][tm][3], 0.f));
                acc3[tm] = __builtin_amdgcn_mfma_f32_16x16x16bf16_1k(a3, pk.s, acc3[tm], 0, 0, 0);
            }
        }

        // epilogue: rows 0 (scale) / 1 (translation) live in quad 0, regs 0/1 -- fp32 stores
        if (quad == 0) {
            #pragma unroll
            for (int tm = 0; tm < 4; ++tm) {
                const size_t r = (size_t)(rowbase + 16 * tm + lq);
                float s  = fminf(fmaxf(acc3[tm][0], -5.f), 5.f);
                float tr = acc3[tm][1];
                out[r * 64 + net] = s;
                out[(size_t)BATCH * 64 + r * 64 + net] = tr;
            }
        }
    }
}

extern "C" void kernel_launch(void* const* d_in, const int* in_sizes, int n_in,
                              void* d_out, int out_size, void* d_ws, size_t ws_size,
                              hipStream_t stream) {
    arnet_kernel<<<dim3(64 * 32), dim3(256), 0, stream>>>(
        (const float*)d_in[0],  // x
        (const float*)d_in[1],  // w0
        (const float*)d_in[2],  // b0
        (const float*)d_in[3],  // v0
        (const float*)d_in[4],  // c0
        (const float*)d_in[5],  // W1
        (const float*)d_in[6],  // B1
        (const float*)d_in[7],  // W2
        (const float*)d_in[8],  // B2
        (const float*)d_in[9],  // W3
        (const float*)d_in[10], // B3
        (float*)d_out);
}

// Round 5
// 134.402 us; speedup vs baseline: 1.1104x; 1.1104x over previous
//
#include <hip/hip_runtime.h>
#include <hip/hip_bf16.h>

#define BATCH 16384

typedef __attribute__((ext_vector_type(8))) short short8;
typedef __attribute__((ext_vector_type(4))) short short4v;
typedef __attribute__((ext_vector_type(8))) unsigned short ushort8;
typedef __attribute__((ext_vector_type(4))) unsigned short ushort4v;
typedef __attribute__((ext_vector_type(4))) float float4v;

// ---- d_ws layout (bytes) ----
#define WS_XBF   0u               // x as bf16 [16384][64]                  = 2 MB
#define WS_A1    2097152u         // [63][th:4][lane:64][32B]  (a10|a11)    = 516096 B
#define WS_A2    2613248u         // [63][lane:64][tg:4][th:4][8B]          = 516096 B
#define WS_A3    3129344u         // [63][lane:64][tg:4][8B]                = 129024 B
#define WS_NEED  3258368u

__device__ __forceinline__ unsigned int packbf2(float a, float b) {
    union { __hip_bfloat162 h; unsigned int u; } v;
    v.h = __float22bfloat162_rn(make_float2(a, b));
    return v.u;
}
__device__ __forceinline__ unsigned short f2bf(float a) {
    union { __hip_bfloat16 h; unsigned short u; } v;
    v.h = __float2bfloat16(a);
    return v.u;
}

// ---------------- prep: x -> bf16, weights -> per-lane A-fragment images ----------------
__global__ __launch_bounds__(256) void prep_kernel(
    const float* __restrict__ x,   // [16384,64]
    const float* __restrict__ W1,  // [63,64,64] [d][h]
    const float* __restrict__ W2,  // [63,64,64] [h][g]
    const float* __restrict__ W3,  // [63,64,2]  [g][o]
    char* __restrict__ ws)
{
    const int b = blockIdx.x;
    const int t = threadIdx.x;

    if (b >= 63) {
        // x convert: 8 floats per thread
        const int idx = (b - 63) * 256 + t;          // 0 .. 131071
        const float* xp = x + (size_t)idx * 8;
        float4v f0 = *(const float4v*)(xp);
        float4v f1 = *(const float4v*)(xp + 4);
        union { ushort8 s; unsigned int u[4]; } p;
        p.u[0] = packbf2(f0[0], f0[1]);
        p.u[1] = packbf2(f0[2], f0[3]);
        p.u[2] = packbf2(f1[0], f1[1]);
        p.u[3] = packbf2(f1[2], f1[3]);
        *(ushort8*)(ws + WS_XBF + (size_t)idx * 16) = p.s;
        return;
    }

    const int kn   = b;
    const int net  = kn + 1;
    const int lane = t & 63;
    const int grp  = t >> 6;       // serves as th (A1) and tg (A2/A3)
    const int lq   = lane & 15;
    const int quad = lane >> 4;

    // A1 fragment: A[m=h=lq+16*th][k=d=quad*8+j (a10) / +32 (a11)], masked d<net
    {
        const int h = lq + 16 * grp;
        ushort8 a10, a11;
        #pragma unroll
        for (int j = 0; j < 8; ++j) {
            const int d0 = quad * 8 + j;
            const int d1 = d0 + 32;
            a10[j] = (d0 < net) ? f2bf(W1[kn * 4096 + d0 * 64 + h]) : (unsigned short)0;
            a11[j] = (d1 < net) ? f2bf(W1[kn * 4096 + d1 * 64 + h]) : (unsigned short)0;
        }
        char* dst = ws + WS_A1 + kn * 8192 + grp * 2048 + lane * 32;
        *(ushort8*)(dst)      = a10;
        *(ushort8*)(dst + 16) = a11;
    }

    // A2 fragment (_1k): A[m=g=lq+16*tg][k=h=quad*4+16*th+i]
    {
        const int g = lq + 16 * grp;
        #pragma unroll
        for (int th = 0; th < 4; ++th) {
            ushort4v v;
            #pragma unroll
            for (int i = 0; i < 4; ++i) {
                const int h = quad * 4 + 16 * th + i;
                v[i] = f2bf(W2[kn * 4096 + h * 64 + g]);
            }
            *(ushort4v*)(ws + WS_A2 + kn * 8192 + lane * 128 + grp * 32 + th * 8) = v;
        }
    }

    // A3 fragment (_1k): A[m=o=lq (0/1)][k=g=quad*4+16*tg+i], rows >=2 zero
    {
        ushort4v v;
        #pragma unroll
        for (int i = 0; i < 4; ++i) {
            const int g = quad * 4 + 16 * grp + i;
            v[i] = (lq < 2) ? f2bf(W3[kn * 128 + g * 2 + lq]) : (unsigned short)0;
        }
        *(ushort4v*)(ws + WS_A3 + kn * 2048 + lane * 32 + grp * 8) = v;
    }
}

// ---------------- main: LDS-free register-chained MLP ----------------
__global__ __launch_bounds__(256, 4) void arnet_main(
    const float* __restrict__ w0, const float* __restrict__ b0,
    const float* __restrict__ v0, const float* __restrict__ c0,
    const float* __restrict__ B1, const float* __restrict__ B2,
    const float* __restrict__ B3,
    const char* __restrict__ ws,
    float* __restrict__ out)
{
    const int bi = blockIdx.x;
    const int t  = threadIdx.x;

    if (bi < 64) {
        // constant network 0: one 256-row tile per block, one row per thread
        float s = 0.f, tr = 0.f;
        #pragma unroll 8
        for (int j = 0; j < 64; ++j) {
            float h = fmaxf(w0[j] + b0[j], 0.f);
            s  += h * v0[2 * j];
            tr += h * v0[2 * j + 1];
        }
        s += c0[0];
        tr += c0[1];
        s = fminf(fmaxf(s, -5.f), 5.f);
        const size_t r = (size_t)bi * 256 + t;
        out[r * 64] = s;
        out[(size_t)BATCH * 64 + r * 64] = tr;
        return;
    }

    const int bb    = bi - 64;
    const int kn    = bb >> 6;       // 0..62
    const int chunk = bb & 63;       // 256-row chunk
    const int net   = kn + 1;

    const int lane = t & 63;
    const int w    = t >> 6;
    const int lq   = lane & 15;
    const int quad = lane >> 4;

    // persistent weight fragments (coalesced 8B loads, L2-hot across the 64 tile-blocks)
    short4v A2r[4][4];
    #pragma unroll
    for (int tg = 0; tg < 4; ++tg)
        #pragma unroll
        for (int th = 0; th < 4; ++th)
            A2r[tg][th] = *(const short4v*)(ws + WS_A2 + kn * 8192 + lane * 128 + tg * 32 + th * 8);
    short4v A3r[4];
    #pragma unroll
    for (int tg = 0; tg < 4; ++tg)
        A3r[tg] = *(const short4v*)(ws + WS_A3 + kn * 2048 + lane * 32 + tg * 8);

    const float b30 = B3[kn * 2];
    const float b31 = B3[kn * 2 + 1];
    const unsigned short* pA1 = (const unsigned short*)(ws + WS_A1 + kn * 8192);
    const char* xb = ws + WS_XBF;

    for (int pass = 0; pass < 2; ++pass) {
        const int rowbase = chunk * 256 + w * 64 + pass * 32;

        // B of L1 = XT, already bf16: 16B/lane fully-coalesced loads
        short8 xf[2][2];
        #pragma unroll
        for (int tm = 0; tm < 2; ++tm) {
            const char* base = xb + (size_t)(rowbase + 16 * tm + lq) * 128 + quad * 16;
            xf[tm][0] = *(const short8*)(base);
            xf[tm][1] = *(const short8*)(base + 64);
        }

        // layer-2 accumulators, bias-initialized
        float4v acc2[4][2];
        #pragma unroll
        for (int tg = 0; tg < 4; ++tg) {
            float4v bias2 = *(const float4v*)(B2 + kn * 64 + quad * 4 + 16 * tg);
            acc2[tg][0] = bias2;
            acc2[tg][1] = bias2;
        }

        #pragma unroll
        for (int th = 0; th < 4; ++th) {
            const unsigned short* a1p = pA1 + th * 1024 + lane * 16;   // halves
            short8 a10 = *(const short8*)(a1p);
            short8 a11 = *(const short8*)(a1p + 8);
            float4v bias1 = *(const float4v*)(B1 + kn * 64 + quad * 4 + 16 * th);
            short4v bf1[2];
            #pragma unroll
            for (int tm = 0; tm < 2; ++tm) {
                float4v acc1 = bias1;
                acc1 = __builtin_amdgcn_mfma_f32_16x16x32_bf16(a10, xf[tm][0], acc1, 0, 0, 0);
                acc1 = __builtin_amdgcn_mfma_f32_16x16x32_bf16(a11, xf[tm][1], acc1, 0, 0, 0);
                union { short4v s; unsigned int u[2]; } pk;
                pk.u[0] = packbf2(fmaxf(acc1[0], 0.f), fmaxf(acc1[1], 0.f));
                pk.u[1] = packbf2(fmaxf(acc1[2], 0.f), fmaxf(acc1[3], 0.f));
                bf1[tm] = pk.s;
            }
            #pragma unroll
            for (int tg = 0; tg < 4; ++tg)
                #pragma unroll
                for (int tm = 0; tm < 2; ++tm)
                    acc2[tg][tm] = __builtin_amdgcn_mfma_f32_16x16x16bf16_1k(A2r[tg][th], bf1[tm], acc2[tg][tm], 0, 0, 0);
        }

        // layer 3
        float4v acc3[2];
        #pragma unroll
        for (int tm = 0; tm < 2; ++tm) {
            acc3[tm][0] = b30; acc3[tm][1] = b31; acc3[tm][2] = 0.f; acc3[tm][3] = 0.f;
        }
        #pragma unroll
        for (int tg = 0; tg < 4; ++tg)
            #pragma unroll
            for (int tm = 0; tm < 2; ++tm) {
                union { short4v s; unsigned int u[2]; } pk;
                pk.u[0] = packbf2(fmaxf(acc2[tg][tm][0], 0.f), fmaxf(acc2[tg][tm][1], 0.f));
                pk.u[1] = packbf2(fmaxf(acc2[tg][tm][2], 0.f), fmaxf(acc2[tg][tm][3], 0.f));
                acc3[tm] = __builtin_amdgcn_mfma_f32_16x16x16bf16_1k(A3r[tg], pk.s, acc3[tm], 0, 0, 0);
            }

        if (quad == 0) {
            #pragma unroll
            for (int tm = 0; tm < 2; ++tm) {
                const size_t r = (size_t)(rowbase + 16 * tm + lq);
                out[r * 64 + net] = fminf(fmaxf(acc3[tm][0], -5.f), 5.f);
                out[(size_t)BATCH * 64 + r * 64 + net] = acc3[tm][1];
            }
        }
    }
}

// ---------------- fallback (R4, verified): used only if ws_size < WS_NEED ----------------
#define WPAD 72
__global__ __launch_bounds__(256) void arnet_fallback(
    const float* __restrict__ x, const float* __restrict__ w0, const float* __restrict__ b0,
    const float* __restrict__ v0, const float* __restrict__ c0,
    const float* __restrict__ W1, const float* __restrict__ B1,
    const float* __restrict__ W2, const float* __restrict__ B2,
    const float* __restrict__ W3, const float* __restrict__ B3,
    float* __restrict__ out)
{
    const int bi = blockIdx.x;
    const int net = bi >> 5;
    const int tile = bi & 31;
    const int t = threadIdx.x;
    if (net == 0) {
        float s = 0.f, tr = 0.f;
        for (int j = 0; j < 64; ++j) {
            float h = fmaxf(w0[j] + b0[j], 0.f);
            s += h * v0[2 * j]; tr += h * v0[2 * j + 1];
        }
        s += c0[0]; tr += c0[1];
        s = fminf(fmaxf(s, -5.f), 5.f);
        const size_t r0 = (size_t)tile * 512;
        out[(r0 + t) * 64] = s; out[(size_t)BATCH * 64 + (r0 + t) * 64] = tr;
        out[(r0 + 256 + t) * 64] = s; out[(size_t)BATCH * 64 + (r0 + 256 + t) * 64] = tr;
        return;
    }
    __shared__ unsigned short sW1T[64 * WPAD];
    __shared__ unsigned short sW2T[64 * WPAD];
    __shared__ unsigned short sW3T[2 * 64];
    __shared__ float sB1[64];
    __shared__ float sB2[64];
    const int kn = net - 1;
    {
        const int hb = (t & 15) * 4, jb = (t >> 4) * 4;
        const float* src1 = W1 + kn * 4096;
        const float* src2 = W2 + kn * 4096;
        float4v a[4], b[4];
        for (int jj = 0; jj < 4; ++jj) {
            a[jj] = *(const float4v*)(src1 + (jb + jj) * 64 + hb);
            if (jb + jj >= net) a[jj] = (float4v)0.f;
            b[jj] = *(const float4v*)(src2 + (jb + jj) * 64 + hb);
        }
        for (int hh = 0; hh < 4; ++hh) {
            ushort4v ra, rb;
            for (int jj = 0; jj < 4; ++jj) { ra[jj] = f2bf(a[jj][hh]); rb[jj] = f2bf(b[jj][hh]); }
            *(ushort4v*)(&sW1T[(hb + hh) * WPAD + jb]) = ra;
            *(ushort4v*)(&sW2T[(hb + hh) * WPAD + jb]) = rb;
        }
    }
    if (t < 64) {
        sW3T[t] = f2bf(W3[kn * 128 + t * 2]);
        sW3T[64 + t] = f2bf(W3[kn * 128 + t * 2 + 1]);
        sB1[t] = B1[kn * 64 + t];
        sB2[t] = B2[kn * 64 + t];
    }
    const float b30 = B3[kn * 2], b31 = B3[kn * 2 + 1];
    __syncthreads();
    const int lane = t & 63, w = t >> 6, lq = lane & 15, quad = lane >> 4;
    for (int pass = 0; pass < 2; ++pass) {
        const int rowbase = tile * 512 + pass * 256 + w * 64;
        short8 xf[4][2];
        for (int tm = 0; tm < 4; ++tm) {
            const float* xr = x + (size_t)(rowbase + 16 * tm + lq) * 64 + quad * 8;
            for (int half = 0; half < 2; ++half) {
                float4v f0 = *(const float4v*)(xr + 32 * half);
                float4v f1 = *(const float4v*)(xr + 32 * half + 4);
                union { short8 s; unsigned int u[4]; } p;
                p.u[0] = packbf2(f0[0], f0[1]); p.u[1] = packbf2(f0[2], f0[3]);
                p.u[2] = packbf2(f1[0], f1[1]); p.u[3] = packbf2(f1[2], f1[3]);
                xf[tm][half] = p.s;
            }
        }
        float4v acc2[4][4];
        for (int tg = 0; tg < 4; ++tg) {
            float4v bias2 = *(const float4v*)(&sB2[quad * 4 + 16 * tg]);
            for (int tm = 0; tm < 4; ++tm) acc2[tg][tm] = bias2;
        }
        for (int th = 0; th < 4; ++th) {
            float4v bias1 = *(const float4v*)(&sB1[quad * 4 + 16 * th]);
            short8 a10 = *(const short8*)(&sW1T[(lq + 16 * th) * WPAD + quad * 8]);
            short8 a11 = *(const short8*)(&sW1T[(lq + 16 * th) * WPAD + quad * 8 + 32]);
            float4v acc1[4];
            for (int tm = 0; tm < 4; ++tm) {
                acc1[tm] = bias1;
                acc1[tm] = __builtin_amdgcn_mfma_f32_16x16x32_bf16(a10, xf[tm][0], acc1[tm], 0, 0, 0);
                acc1[tm] = __builtin_amdgcn_mfma_f32_16x16x32_bf16(a11, xf[tm][1], acc1[tm], 0, 0, 0);
            }
            short4v bf1[4];
            for (int tm = 0; tm < 4; ++tm) {
                union { short4v s; unsigned int u[2]; } pk;
                pk.u[0] = packbf2(fmaxf(acc1[tm][0], 0.f), fmaxf(acc1[tm][1], 0.f));
                pk.u[1] = packbf2(fmaxf(acc1[tm][2], 0.f), fmaxf(acc1[tm][3], 0.f));
                bf1[tm] = pk.s;
            }
            for (int tg = 0; tg < 4; ++tg) {
                short4v a2 = *(const short4v*)(&sW2T[(lq + 16 * tg) * WPAD + quad * 4 + 16 * th]);
                for (int tm = 0; tm < 4; ++tm)
                    acc2[tg][tm] = __builtin_amdgcn_mfma_f32_16x16x16bf16_1k(a2, bf1[tm], acc2[tg][tm], 0, 0, 0);
            }
        }
        float4v acc3[4];
        for (int tm = 0; tm < 4; ++tm) { acc3[tm][0] = b30; acc3[tm][1] = b31; acc3[tm][2] = 0.f; acc3[tm][3] = 0.f; }
        for (int tg = 0; tg < 4; ++tg) {
            short4v a3 = (short4v)0;
            if (lq < 2) a3 = *(const short4v*)(&sW3T[lq * 64 + quad * 4 + 16 * tg]);
            for (int tm = 0; tm < 4; ++tm) {
                union { short4v s; unsigned int u[2]; } pk;
                pk.u[0] = packbf2(fmaxf(acc2[tg][tm][0], 0.f), fmaxf(acc2[tg][tm][1], 0.f));
                pk.u[1] = packbf2(fmaxf(acc2[tg][tm][2], 0.f), fmaxf(acc2[tg][tm][3], 0.f));
                acc3[tm] = __builtin_amdgcn_mfma_f32_16x16x16bf16_1k(a3, pk.s, acc3[tm], 0, 0, 0);
            }
        }
        if (quad == 0) {
            for (int tm = 0; tm < 4; ++tm) {
                const size_t r = (size_t)(rowbase + 16 * tm + lq);
                out[r * 64 + net] = fminf(fmaxf(acc3[tm][0], -5.f), 5.f);
                out[(size_t)BATCH * 64 + r * 64 + net] = acc3[tm][1];
            }
        }
    }
}

extern "C" void kernel_launch(void* const* d_in, const int* in_sizes, int n_in,
                              void* d_out, int out_size, void* d_ws, size_t ws_size,
                              hipStream_t stream) {
    const float* x  = (const float*)d_in[0];
    const float* w0 = (const float*)d_in[1];
    const float* b0 = (const float*)d_in[2];
    const float* v0 = (const float*)d_in[3];
    const float* c0 = (const float*)d_in[4];
    const float* W1 = (const float*)d_in[5];
    const float* B1 = (const float*)d_in[6];
    const float* W2 = (const float*)d_in[7];
    const float* B2 = (const float*)d_in[8];
    const float* W3 = (const float*)d_in[9];
    const float* B3 = (const float*)d_in[10];
    float* out = (float*)d_out;

    if (ws_size >= WS_NEED) {
        prep_kernel<<<dim3(63 + 512), dim3(256), 0, stream>>>(x, W1, W2, W3, (char*)d_ws);
        arnet_main<<<dim3(64 + 63 * 64), dim3(256), 0, stream>>>(
            w0, b0, v0, c0, B1, B2, B3, (const char*)d_ws, out);
    } else {
        arnet_fallback<<<dim3(64 * 32), dim3(256), 0, stream>>>(
            x, w0, b0, v0, c0, W1, B1, W2, B2, W3, B3, out);
    }
}